// Round 4
// baseline (678.424 us; speedup 1.0000x reference)
//
#include <hip/hip_runtime.h>
#include <math.h>

#define KDIM 128
#define TLEN 512
#define BATCH 16
#define CH_L 16
#define NCH 32           // segments (replay blocks) per batch
#define NMAT 31          // chunk matrices: segment x covers t in [16x+1, 16x+16]

typedef _Float16 half8 __attribute__((ext_vector_type(8)));
typedef _Float16 half4 __attribute__((ext_vector_type(4)));
typedef _Float16 half2t __attribute__((ext_vector_type(2)));
typedef float floatx4 __attribute__((ext_vector_type(4)));

#if defined(__has_builtin)
#if __has_builtin(__builtin_amdgcn_fdot2)
#define HAVE_FDOT2 1
#endif
#endif

static __device__ __forceinline__ float dot2f(half2t a, half2t b, float c) {
#ifdef HAVE_FDOT2
    return __builtin_amdgcn_fdot2(a, b, c, false);
#else
    return fmaf((float)a[0], (float)b[0], fmaf((float)a[1], (float)b[1], c));
#endif
}

// acc += dot(packed-f16 w (4 VGPRs = 8 halfs), half8 v)
static __device__ __forceinline__ float dot8(const half8 v, const float4 w, float acc) {
    const uint4 r = __builtin_bit_cast(uint4, v);
    acc = dot2f(__builtin_bit_cast(half2t, w.x), __builtin_bit_cast(half2t, r.x), acc);
    acc = dot2f(__builtin_bit_cast(half2t, w.y), __builtin_bit_cast(half2t, r.y), acc);
    acc = dot2f(__builtin_bit_cast(half2t, w.z), __builtin_bit_cast(half2t, r.z), acc);
    acc = dot2f(__builtin_bit_cast(half2t, w.w), __builtin_bit_cast(half2t, r.w), acc);
    return acc;
}

// async global->LDS, 16 B per lane; LDS dest = wave-uniform base + lane*16
static __device__ __forceinline__ void gload_lds16(const _Float16* g, _Float16* l) {
    __builtin_amdgcn_global_load_lds(
        (const __attribute__((address_space(1))) void*)g,
        (__attribute__((address_space(3))) void*)l, 16, 0, 0);
}

// ---------------- workspace layouts (bytes) ----------------
// FUSED path: tiny — no Pst round trip at all.
#define FUS_AENT  0               // f32 [BATCH][NCH][KDIM] = 262144
#define FUS_FLAG  262144          // u32 [BATCH][NCH]       = 2048
#define FUS_NEED  264192
// 3-kernel hedge path (R2 proven):
#define WSN_PST   0
#define WSN_SVEC  16252928
#define WSN_AENT  16506880
#define WSN_NEED  16769024

// Frag conventions (validated):
//  A-frag tile(mt,kt): lane(quad,lm) holds A[mt*16+lm][kt*32+quad*8 .. +8]
//  B-frag tile(kt,nt): lane(quad,lm) holds B[kt*32+quad*8 .. +8][nt*16+lm]
//  C/D  tile(mt,nt):   lane(quad,lm) reg q = C[mt*16+quad*4+q][nt*16+lm]

// ============================================================================
// FUSED pipeline: chunk-product + flag-chained scan + replay in ONE dispatch.
// Grid (NCH=32, BATCH=16) = 512 blocks x 256 thr, 80KB LDS -> exactly 2/CU.
// Launched with hipLaunchCooperativeKernel => co-residency guaranteed (or the
// launch errors and we fall back). Scan chain: block x polls flags[b][x]
// (set by block x-1 after writing aEnter[b][x]); waits are forward-only and
// all blocks resident => acyclic => no deadlock. Pst (16MB W + 16MB R) gone.
// ============================================================================
__global__ __launch_bounds__(256, 2) void crf_fused(
    const float* __restrict__ trans, const float* __restrict__ em,
    const int* __restrict__ seq_lens, float* __restrict__ aEnter,
    unsigned int* __restrict__ flags, float* __restrict__ alpha,
    float* __restrict__ logZ)
{
    const int x = blockIdx.x;      // segment 0..31
    const int b = blockIdx.y;
    const int tid = threadIdx.x;
    const int w = tid >> 6, lane = tid & 63;
    const int quad = lane >> 4, lm = lane & 15;

    // F[m][k] = exp(trans[k][m]); row stride 136 halfs; 8-half row pad (16B)
    // doubles as f32 scratch: padF(n,0)=per-col scale, padF(.,1)=reduce, 
    // padF(n,2)=scan p~.
    __shared__ __align__(16) _Float16 Flds[128 * 136];   // 34,816 B
    // Per-wave running product, B-layout [n_local][m] (regions nt*2176+lm*136);
    // spare tail [4352..4608) = f32[128] scan partial. Phase 3 reuses [0..]:
    // Wscr[0]=p_lds f16[128], Wscr[1]=part f32[128], Wscr[2]=sig.
    __shared__ __align__(16) _Float16 Wscr[4][4608];     // 36,864 B
    __shared__ __align__(16) float gAll[16 * KDIM];      // 8,192 B  exp(em rows t0..)
    // total 79,872 B -> 2 blocks/CU

    const int t0 = x * CH_L + 1;
    const float* emb = em + (size_t)b * TLEN * KDIM;
    float* outb = alpha + (size_t)b * TLEN * KDIM;
    const int len = seq_lens[b];

    auto padF = [&](int n, int s) -> float& {
        return *reinterpret_cast<float*>(
            reinterpret_cast<char*>(Flds) + 272 * n + 256 + 4 * s);
    };

    // ---- stage F (transposed exp(trans)) ----
    {
        const int m = tid & 127, kh = tid >> 7;
        #pragma unroll
        for (int kk = 0; kk < 8; ++kk) {
            const int k0 = kh * 64 + kk * 8;
            half8 o;
            #pragma unroll
            for (int j = 0; j < 8; ++j)
                o[j] = (_Float16)__expf(trans[(k0 + j) * KDIM + m]);
            *(half8*)&Flds[m * 136 + k0] = o;
        }
    }
    // ---- stage g = exp(em[t0 .. t0+15]) (x=31 has only 15 valid rows) ----
    {
        const int i8 = tid * 8;
        if (t0 + (i8 >> 7) < TLEN) {
            const float4 e0 = *(const float4*)&emb[t0 * KDIM + i8];
            const float4 e1 = *(const float4*)&emb[t0 * KDIM + i8 + 4];
            float4 g0, g1;
            g0.x = __expf(e0.x); g0.y = __expf(e0.y); g0.z = __expf(e0.z); g0.w = __expf(e0.w);
            g1.x = __expf(e1.x); g1.y = __expf(e1.y); g1.z = __expf(e1.z); g1.w = __expf(e1.w);
            *(float4*)&gAll[i8] = g0;
            *(float4*)&gAll[i8 + 4] = g1;
        }
    }
    __syncthreads();

    // ================= phase 1: chunk product (R2-proven loop) ==============
    if (x < NMAT) {
        _Float16* Wb = Wscr[w];
        float sc[2];
        half8 Bf[4][2];

        #pragma unroll
        for (int nt = 0; nt < 2; ++nt) {
            float tv[4][8];
            float cm = 0.f;
            const int n = 32 * w + nt * 16 + lm;
            #pragma unroll
            for (int kt = 0; kt < 4; ++kt) {
                const int r0 = kt * 32 + quad * 8;
                const float4 ga = *(const float4*)&gAll[r0];
                const float4 gb = *(const float4*)&gAll[r0 + 4];
                const float gg[8] = {ga.x, ga.y, ga.z, ga.w, gb.x, gb.y, gb.z, gb.w};
                const float4 ta = *(const float4*)&trans[(size_t)n * KDIM + r0];
                const float4 tb = *(const float4*)&trans[(size_t)n * KDIM + r0 + 4];
                const float tt[8] = {ta.x, ta.y, ta.z, ta.w, tb.x, tb.y, tb.z, tb.w};
                #pragma unroll
                for (int j = 0; j < 8; ++j) {
                    const float v = __expf(tt[j]) * gg[j];
                    tv[kt][j] = v;
                    cm = fmaxf(cm, v);
                }
            }
            cm = fmaxf(cm, __shfl_xor(cm, 16));
            cm = fmaxf(cm, __shfl_xor(cm, 32));
            const float ri = 1.0f / cm;
            sc[nt] = __logf(cm);
            #pragma unroll
            for (int kt = 0; kt < 4; ++kt)
                #pragma unroll
                for (int j = 0; j < 8; ++j)
                    Bf[kt][nt][j] = (_Float16)(tv[kt][j] * ri);
        }

        half8 Af[8][4];
        #pragma unroll
        for (int mt = 0; mt < 8; ++mt)
            #pragma unroll
            for (int kt = 0; kt < 4; ++kt)
                Af[mt][kt] = *(const half8*)&Flds[lm * 136 + quad * 8 + mt * 2176 + kt * 32];

        const floatx4 z4 = {0.f, 0.f, 0.f, 0.f};
        for (int it = 1; it < 16; ++it) {
            #pragma unroll
            for (int nt = 0; nt < 2; ++nt) {
                floatx4 acc[8];
                #pragma unroll
                for (int mt = 0; mt < 8; ++mt)
                    acc[mt] = __builtin_amdgcn_mfma_f32_16x16x32_f16(Af[mt][0], Bf[0][nt], z4, 0, 0, 0);
                #pragma unroll
                for (int kt = 1; kt < 4; ++kt)
                    #pragma unroll
                    for (int mt = 0; mt < 8; ++mt)
                        acc[mt] = __builtin_amdgcn_mfma_f32_16x16x32_f16(Af[mt][kt], Bf[kt][nt], acc[mt], 0, 0, 0);

                const float* g = &gAll[it * KDIM];
                float cm = 0.f;
                #pragma unroll
                for (int mt = 0; mt < 8; ++mt) {
                    const float4 gv = *(const float4*)&g[mt * 16 + quad * 4];
                    floatx4 v = acc[mt];
                    v.x *= gv.x; v.y *= gv.y; v.z *= gv.z; v.w *= gv.w;
                    acc[mt] = v;
                    cm = fmaxf(cm, fmaxf(fmaxf(v.x, v.y), fmaxf(v.z, v.w)));
                }
                cm = fmaxf(cm, __shfl_xor(cm, 16));
                cm = fmaxf(cm, __shfl_xor(cm, 32));
                const float ri = 1.0f / cm;
                sc[nt] += __logf(cm);

                // C -> B relayout (same-wave region; compiler orders DS ops)
                #pragma unroll
                for (int mt = 0; mt < 8; ++mt) {
                    const floatx4 v = acc[mt];
                    half4 o;
                    o[0] = (_Float16)(v.x * ri);
                    o[1] = (_Float16)(v.y * ri);
                    o[2] = (_Float16)(v.z * ri);
                    o[3] = (_Float16)(v.w * ri);
                    *(half4*)&Wb[lm * 136 + quad * 4 + nt * 2176 + mt * 16] = o;
                }
            }
            if (it < 15) {
                #pragma unroll
                for (int kt = 0; kt < 4; ++kt)
                    #pragma unroll
                    for (int nt = 0; nt < 2; ++nt)
                        Bf[kt][nt] = *(const half8*)&Wb[lm * 136 + quad * 8 + nt * 2176 + kt * 32];
            }
        }

        if (quad == 0) {
            padF(32 * w + lm, 0) = sc[0];
            padF(32 * w + 16 + lm, 0) = sc[1];
        }
    }

    // ================= phase 2: flag-chained scan step ======================
    if (x > 0) {
        if (tid == 0) {
            while (__hip_atomic_load(&flags[b * NCH + x], __ATOMIC_ACQUIRE,
                                     __HIP_MEMORY_SCOPE_AGENT) == 0u)
                __builtin_amdgcn_s_sleep(2);
        }
    }
    __syncthreads();   // also publishes scS pads block-wide

    const float* aEnt_x = aEnter + ((size_t)(b * NCH + x)) * KDIM;

    if (x < NMAT) {
        // block max of (a_enter + sc)
        const int n7 = tid & 127;
        {
            float av = (x == 0) ? emb[n7] : aEnt_x[n7];
            float v = av + padF(n7, 0);
            #pragma unroll
            for (int o = 32; o; o >>= 1) v = fmaxf(v, __shfl_xor(v, o));
            if (lane == 0) padF(w, 1) = v;
        }
        __syncthreads();
        const float mx = fmaxf(fmaxf(padF(0, 1), padF(1, 1)),
                               fmaxf(padF(2, 1), padF(3, 1)));

        // wave-local p~ for its 32 enter-cols
        if (lane < 32) {
            const int gn = 32 * w + lane;
            const float a2 = (x == 0) ? emb[gn] : aEnt_x[gn];
            padF(gn, 2) = __expf(a2 + padF(gn, 0) - mx);
        }
        // matvec partial: out m-slice lm*8..+7 over this wave's 32 n's
        float ac[8] = {0.f, 0.f, 0.f, 0.f, 0.f, 0.f, 0.f, 0.f};
        _Float16* Wb = Wscr[w];
        #pragma unroll
        for (int s = 0; s < 8; ++s) {
            const int nl = s * 4 + quad;
            const half8 hv = *(const half8*)&Wb[(nl >> 4) * 2176 + (nl & 15) * 136 + lm * 8];
            const float pp = padF(32 * w + nl, 2);
            #pragma unroll
            for (int e = 0; e < 8; ++e) ac[e] = fmaf(pp, (float)hv[e], ac[e]);
        }
        #pragma unroll
        for (int e = 0; e < 8; ++e) {
            ac[e] += __shfl_xor(ac[e], 16);
            ac[e] += __shfl_xor(ac[e], 32);
        }
        if (quad == 0) {
            float* pPart = (float*)&Wscr[w][4352];
            float4 p0 = {ac[0], ac[1], ac[2], ac[3]};
            float4 p1 = {ac[4], ac[5], ac[6], ac[7]};
            *(float4*)&pPart[lm * 8] = p0;
            *(float4*)&pPart[lm * 8 + 4] = p1;
        }
        __syncthreads();
        if (tid < KDIM) {
            const float q = ((float*)&Wscr[0][4352])[tid] + ((float*)&Wscr[1][4352])[tid]
                          + ((float*)&Wscr[2][4352])[tid] + ((float*)&Wscr[3][4352])[tid];
            aEnter[((size_t)(b * NCH + x + 1)) * KDIM + tid] = mx + __logf(q);
        }
        __threadfence();
        __syncthreads();
        if (tid == 0)
            __hip_atomic_store(&flags[b * NCH + x + 1], 1u, __ATOMIC_RELEASE,
                               __HIP_MEMORY_SCOPE_AGENT);
    }

    // ================= phase 3: replay 16 steps (fallback-style, 4 waves) ===
    const int m = tid & 127, h = tid >> 7;
    half8 Fh[8];
    #pragma unroll
    for (int i = 0; i < 8; ++i)
        Fh[i] = *(const half8*)&Flds[m * 136 + h * 64 + i * 8];

    const float a0 = (x == 0) ? emb[m] : aEnt_x[m];

    _Float16* pL = &Wscr[0][0];
    float* part  = (float*)&Wscr[1][0];
    float* sig   = (float*)&Wscr[2][0];

    {
        float v = a0;
        #pragma unroll
        for (int o = 32; o; o >>= 1) v = fmaxf(v, __shfl_xor(v, o));
        if (lane == 0) padF(4 + w, 1) = v;
    }
    __syncthreads();
    float L = fmaxf(fmaxf(padF(4, 1), padF(5, 1)), fmaxf(padF(6, 1), padF(7, 1)));
    if (h == 0) {
        pL[m] = (_Float16)__expf(a0 - L);
        if (x == 0) outb[m] = a0;
    }
    float la = -INFINITY;
    if (x == 0 && h == 0 && len == 1) la = a0;

    const int steps = (x == NCH - 1) ? 15 : 16;
    for (int t = 1; t <= steps; ++t) {
        const int tt = 16 * x + t;
        __syncthreads();                       // pL ready
        float eraw = 0.f;
        if (h == 0) eraw = emb[tt * KDIM + m];
        float qp = 0.f;
        #pragma unroll
        for (int i = 0; i < 8; ++i)
            qp = dot8(Fh[i], *(const float4*)&pL[h * 64 + i * 8], qp);
        if (h) part[m] = qp;
        __syncthreads();
        float q = 0.f;
        if (!h) {
            q = qp + part[m];
            const float A = eraw + L + __logf(q);
            outb[tt * KDIM + m] = A;
            if (tt == len - 1) la = A;
            if (m == 0) sig[0] = q;
        }
        __syncthreads();
        const float sg = sig[0];
        if (!h) pL[m] = (_Float16)(q * (1.0f / sg) * gAll[(t - 1) * KDIM + m]);
        L += __logf(sg);
    }

    // ---- logZ (block owning t = len-1) ----
    const int xown = (len == 1) ? 0 : ((len - 2) >> 4);
    if (x == xown) {
        float mz = la;
        #pragma unroll
        for (int o = 32; o; o >>= 1) mz = fmaxf(mz, __shfl_xor(mz, o));
        if (lane == 0) padF(w, 1) = mz;
        __syncthreads();
        mz = fmaxf(fmaxf(padF(0, 1), padF(1, 1)), fmaxf(padF(2, 1), padF(3, 1)));
        float e = (h == 0) ? __expf(la - mz) : 0.f;
        #pragma unroll
        for (int o = 32; o; o >>= 1) e += __shfl_xor(e, o);
        if (lane == 0) padF(4 + w, 1) = e;
        __syncthreads();
        if (tid == 0)
            logZ[b] = mz + __logf(padF(4, 1) + padF(5, 1) + padF(6, 1) + padF(7, 1));
    }
}

// ======================= 3-kernel hedge path (R2 proven) ======================
__global__ __launch_bounds__(256, 2) void crf_chunkcols2(
    const float* __restrict__ trans, const float* __restrict__ em,
    _Float16* __restrict__ Pst, float* __restrict__ Svec)
{
    const int c = blockIdx.x;
    const int b = blockIdx.y;
    const int tid = threadIdx.x;
    const int w = tid >> 6, lane = tid & 63;
    const int quad = lane >> 4, lm = lane & 15;

    __shared__ __align__(16) _Float16 Flds[128 * 136];
    __shared__ __align__(16) _Float16 Wscr[4][4608];
    __shared__ __align__(16) float gAll[16 * KDIM];

    const int t0 = c * CH_L + 1;
    const float* emb = em + (size_t)b * TLEN * KDIM;

    {
        const int m = tid & 127, kh = tid >> 7;
        #pragma unroll
        for (int kk = 0; kk < 8; ++kk) {
            const int k0 = kh * 64 + kk * 8;
            half8 o;
            #pragma unroll
            for (int j = 0; j < 8; ++j)
                o[j] = (_Float16)__expf(trans[(k0 + j) * KDIM + m]);
            *(half8*)&Flds[m * 136 + k0] = o;
        }
    }
    {
        const int i8 = tid * 8;
        const float4 e0 = *(const float4*)&emb[t0 * KDIM + i8];
        const float4 e1 = *(const float4*)&emb[t0 * KDIM + i8 + 4];
        float4 g0, g1;
        g0.x = __expf(e0.x); g0.y = __expf(e0.y); g0.z = __expf(e0.z); g0.w = __expf(e0.w);
        g1.x = __expf(e1.x); g1.y = __expf(e1.y); g1.z = __expf(e1.z); g1.w = __expf(e1.w);
        *(float4*)&gAll[i8] = g0;
        *(float4*)&gAll[i8 + 4] = g1;
    }
    __syncthreads();

    _Float16* Wb = Wscr[w];
    float sc[2];
    half8 Bf[4][2];

    #pragma unroll
    for (int nt = 0; nt < 2; ++nt) {
        float tv[4][8];
        float cm = 0.f;
        const int n = 32 * w + nt * 16 + lm;
        #pragma unroll
        for (int kt = 0; kt < 4; ++kt) {
            const int r0 = kt * 32 + quad * 8;
            const float4 ga = *(const float4*)&gAll[r0];
            const float4 gb = *(const float4*)&gAll[r0 + 4];
            const float gg[8] = {ga.x, ga.y, ga.z, ga.w, gb.x, gb.y, gb.z, gb.w};
            const float4 ta = *(const float4*)&trans[(size_t)n * KDIM + r0];
            const float4 tb = *(const float4*)&trans[(size_t)n * KDIM + r0 + 4];
            const float tt[8] = {ta.x, ta.y, ta.z, ta.w, tb.x, tb.y, tb.z, tb.w};
            #pragma unroll
            for (int j = 0; j < 8; ++j) {
                const float v = __expf(tt[j]) * gg[j];
                tv[kt][j] = v;
                cm = fmaxf(cm, v);
            }
        }
        cm = fmaxf(cm, __shfl_xor(cm, 16));
        cm = fmaxf(cm, __shfl_xor(cm, 32));
        const float ri = 1.0f / cm;
        sc[nt] = __logf(cm);
        #pragma unroll
        for (int kt = 0; kt < 4; ++kt)
            #pragma unroll
            for (int j = 0; j < 8; ++j)
                Bf[kt][nt][j] = (_Float16)(tv[kt][j] * ri);
    }

    half8 Af[8][4];
    #pragma unroll
    for (int mt = 0; mt < 8; ++mt)
        #pragma unroll
        for (int kt = 0; kt < 4; ++kt)
            Af[mt][kt] = *(const half8*)&Flds[lm * 136 + quad * 8 + mt * 2176 + kt * 32];

    const floatx4 z4 = {0.f, 0.f, 0.f, 0.f};
    for (int it = 1; it < 16; ++it) {
        #pragma unroll
        for (int nt = 0; nt < 2; ++nt) {
            floatx4 acc[8];
            #pragma unroll
            for (int mt = 0; mt < 8; ++mt)
                acc[mt] = __builtin_amdgcn_mfma_f32_16x16x32_f16(Af[mt][0], Bf[0][nt], z4, 0, 0, 0);
            #pragma unroll
            for (int kt = 1; kt < 4; ++kt)
                #pragma unroll
                for (int mt = 0; mt < 8; ++mt)
                    acc[mt] = __builtin_amdgcn_mfma_f32_16x16x32_f16(Af[mt][kt], Bf[kt][nt], acc[mt], 0, 0, 0);

            const float* g = &gAll[it * KDIM];
            float cm = 0.f;
            #pragma unroll
            for (int mt = 0; mt < 8; ++mt) {
                const float4 gv = *(const float4*)&g[mt * 16 + quad * 4];
                floatx4 v = acc[mt];
                v.x *= gv.x; v.y *= gv.y; v.z *= gv.z; v.w *= gv.w;
                acc[mt] = v;
                cm = fmaxf(cm, fmaxf(fmaxf(v.x, v.y), fmaxf(v.z, v.w)));
            }
            cm = fmaxf(cm, __shfl_xor(cm, 16));
            cm = fmaxf(cm, __shfl_xor(cm, 32));
            const float ri = 1.0f / cm;
            sc[nt] += __logf(cm);

            if (it < 15) {
                #pragma unroll
                for (int mt = 0; mt < 8; ++mt) {
                    const floatx4 v = acc[mt];
                    half4 o;
                    o[0] = (_Float16)(v.x * ri);
                    o[1] = (_Float16)(v.y * ri);
                    o[2] = (_Float16)(v.z * ri);
                    o[3] = (_Float16)(v.w * ri);
                    *(half4*)&Wb[lm * 136 + quad * 4 + nt * 2176 + mt * 16] = o;
                }
            } else {
                #pragma unroll
                for (int mt = 0; mt < 8; ++mt) {
                    const floatx4 v = acc[mt];
                    const int ba = quad * 144 + lm + mt * 576 + nt * 16;
                    Wb[ba]       = (_Float16)(v.x * ri);
                    Wb[ba + 36]  = (_Float16)(v.y * ri);
                    Wb[ba + 72]  = (_Float16)(v.z * ri);
                    Wb[ba + 108] = (_Float16)(v.w * ri);
                }
            }
        }
        if (it < 15) {
            #pragma unroll
            for (int kt = 0; kt < 4; ++kt)
                #pragma unroll
                for (int nt = 0; nt < 2; ++nt)
                    Bf[kt][nt] = *(const half8*)&Wb[lm * 136 + quad * 8 + nt * 2176 + kt * 32];
        }
    }

    _Float16* Pc = Pst + ((size_t)(b * NMAT + c)) * 16384;
    #pragma unroll
    for (int Kl = 0; Kl < 4; ++Kl)
        #pragma unroll
        for (int hh = 0; hh < 2; ++hh) {
            const half4 lo = *(const half4*)&Wb[(2 * lane + hh) * 36 + Kl * 8];
            const half4 hi = *(const half4*)&Wb[(2 * lane + hh) * 36 + Kl * 8 + 4];
            half8 v;
            #pragma unroll
            for (int e = 0; e < 4; ++e) { v[e] = lo[e]; v[4 + e] = hi[e]; }
            const int u = (2 * (4 * w + Kl) + hh) * 64 + lane;
            *(half8*)&Pc[(size_t)u * 8] = v;
        }
    if (quad == 0) {
        float* sp = Svec + ((size_t)(b * NMAT + c)) * KDIM + 32 * w;
        sp[lm] = sc[0];
        sp[lm + 16] = sc[1];
    }
}

__global__ __launch_bounds__(64, 1) void crf_scanw4(
    const float* __restrict__ em, const _Float16* __restrict__ Pst,
    const float* __restrict__ Svec, float* __restrict__ aEnter)
{
    const int b = blockIdx.x;
    const int lane = threadIdx.x;
    const int j0 = 2 * lane;

    __shared__ __align__(16) _Float16 Pbuf[3][16384];
    __shared__ __align__(16) _Float16 pbuf[KDIM];

    const _Float16* Pb = Pst + (size_t)b * NMAT * 16384;
    const float* svb = Svec + (size_t)b * NMAT * KDIM;
    float* aeb = aEnter + (size_t)b * NCH * KDIM;

    #pragma unroll
    for (int i = 0; i < 32; ++i)
        gload_lds16(Pb + i * 512 + lane * 8, &Pbuf[0][i * 512]);
    #pragma unroll
    for (int i = 0; i < 32; ++i)
        gload_lds16(Pb + 16384 + i * 512 + lane * 8, &Pbuf[1][i * 512]);

    float2 a0 = *(const float2*)&em[(size_t)b * TLEN * KDIM + j0];
    float mx = fmaxf(a0.x, a0.y);
    #pragma unroll
    for (int o = 32; o; o >>= 1) mx = fmaxf(mx, __shfl_xor(mx, o));
    *(float2*)&aeb[j0] = a0;
    float lq0 = a0.x - mx, lq1 = a0.y - mx;
    float L = mx;
    float2 sv = *(const float2*)&svb[j0];

    int cb = 0;
    for (int c = 0; c < NMAT; ++c) {
        if (c + 1 < NMAT) {
            asm volatile("s_waitcnt vmcnt(32)" ::: "memory");
        } else {
            asm volatile("s_waitcnt vmcnt(0)" ::: "memory");
        }
        if (c + 2 < NMAT) {
            const _Float16* src = Pb + (size_t)(c + 2) * 16384;
            _Float16* dst = &Pbuf[(cb + 2) % 3][0];
            #pragma unroll
            for (int i = 0; i < 32; ++i)
                gload_lds16(src + i * 512 + lane * 8, &dst[i * 512]);
        }

        const float v0 = lq0 + sv.x, v1 = lq1 + sv.y;
        float M = fmaxf(v0, v1);
        #pragma unroll
        for (int o = 32; o; o >>= 1) M = fmaxf(M, __shfl_xor(M, o));
        half2t p2;
        p2[0] = (_Float16)__expf(v0 - M);
        p2[1] = (_Float16)__expf(v1 - M);
        ((half2t*)pbuf)[lane] = p2;
        if (c + 1 < NMAT) sv = *(const float2*)&svb[(size_t)(c + 1) * KDIM + j0];

        const _Float16* Pcur = &Pbuf[cb][0];
        float q0 = 0.f, q1 = 0.f;
        #pragma unroll
        for (int K = 0; K < 16; ++K) {
            const float4 wv = *(const float4*)&pbuf[K * 8];
            const half8 c0 = *(const half8*)&Pcur[((2 * K + 0) * 64 + lane) * 8];
            const half8 c1 = *(const half8*)&Pcur[((2 * K + 1) * 64 + lane) * 8];
            q0 = dot8(c0, wv, q0);
            q1 = dot8(c1, wv, q1);
        }

        const float base = L + M;
        const float lg0 = __logf(q0), lg1 = __logf(q1);
        float2 st;
        st.x = base + lg0;
        st.y = base + lg1;
        *(float2*)&aeb[(size_t)(c + 1) * KDIM + j0] = st;
        lq0 = lg0;
        lq1 = lg1;
        L = base;
        cb = (cb + 1) % 3;
    }
}

__global__ __launch_bounds__(64, 1) void crf_replayw(
    const float* __restrict__ trans, const float* __restrict__ em,
    const int* __restrict__ seq_lens, const float* __restrict__ aEnter,
    float* __restrict__ alpha, float* __restrict__ logZ)
{
    const int c = blockIdx.x, b = blockIdx.y;
    const int l = threadIdx.x;

    __shared__ __align__(16) _Float16 pbuf[KDIM];

    half2t Ea[64], Eb[64];
    #pragma unroll
    for (int t2 = 0; t2 < 64; ++t2) {
        const float* r0 = &trans[(2 * t2) * KDIM];
        const float* r1 = &trans[(2 * t2 + 1) * KDIM];
        half2t ea, eb;
        ea[0] = (_Float16)__expf(r0[l]);
        ea[1] = (_Float16)__expf(r1[l]);
        eb[0] = (_Float16)__expf(r0[l + 64]);
        eb[1] = (_Float16)__expf(r1[l + 64]);
        Ea[t2] = ea;
        Eb[t2] = eb;
    }

    const int len = seq_lens[b];
    const float* emb = em + (size_t)b * TLEN * KDIM;
    float* outb = alpha + (size_t)b * TLEN * KDIM;
    const float* ae = aEnter + ((size_t)b * NCH + c) * KDIM;

    float a0 = ae[l], a1 = ae[l + 64];
    if (c == 0) {
        a0 = emb[l];
        a1 = emb[l + 64];
    }
    float mx = fmaxf(a0, a1);
    #pragma unroll
    for (int o = 32; o; o >>= 1) mx = fmaxf(mx, __shfl_xor(mx, o));
    float L = mx;
    pbuf[l]      = (_Float16)__expf(a0 - L);
    pbuf[l + 64] = (_Float16)__expf(a1 - L);

    float la0 = 0.f, la1 = -INFINITY;
    if (c == 0) {
        outb[l] = a0;
        outb[l + 64] = a1;
        if (len == 1) { la0 = a0; la1 = a1; }
    }

    const int t_begin = c * CH_L + 1;
    const int t_end = (c == NCH - 1) ? (TLEN - 1) : (c * CH_L + CH_L);

    float e0 = emb[t_begin * KDIM + l];
    float e1 = emb[t_begin * KDIM + l + 64];

    for (int t = t_begin; t <= t_end; ++t) {
        float n0 = 0.f, n1 = 0.f;
        if (t < t_end) {
            n0 = emb[(t + 1) * KDIM + l];
            n1 = emb[(t + 1) * KDIM + l + 64];
        }

        float q0 = 0.f, q1 = 0.f;
        #pragma unroll
        for (int s = 0; s < 16; ++s) {
            const float4 w = *(const float4*)&pbuf[s * 8];
            const half2t p0 = __builtin_bit_cast(half2t, w.x);
            const half2t p1 = __builtin_bit_cast(half2t, w.y);
            const half2t p2 = __builtin_bit_cast(half2t, w.z);
            const half2t p3 = __builtin_bit_cast(half2t, w.w);
            q0 = dot2f(p0, Ea[4 * s + 0], q0);
            q0 = dot2f(p1, Ea[4 * s + 1], q0);
            q0 = dot2f(p2, Ea[4 * s + 2], q0);
            q0 = dot2f(p3, Ea[4 * s + 3], q0);
            q1 = dot2f(p0, Eb[4 * s + 0], q1);
            q1 = dot2f(p1, Eb[4 * s + 1], q1);
            q1 = dot2f(p2, Eb[4 * s + 2], q1);
            q1 = dot2f(p3, Eb[4 * s + 3], q1);
        }

        const float A0 = e0 + L + __logf(q0);
        const float A1 = e1 + L + __logf(q1);
        outb[t * KDIM + l] = A0;
        outb[t * KDIM + l + 64] = A1;
        if (t == len - 1) { la0 = A0; la1 = A1; }

        const float sigma = __shfl(q0, 0);
        const float ri = 1.0f / sigma;
        pbuf[l]      = (_Float16)(q0 * ri * __expf(e0));
        pbuf[l + 64] = (_Float16)(q1 * ri * __expf(e1));
        L += __logf(sigma);
        e0 = n0; e1 = n1;
    }

    const bool blockowns = (len == 1) ? (c == 0) : (((len - 2) >> 4) == c);
    if (blockowns) {
        float m2 = fmaxf(la0, la1);
        #pragma unroll
        for (int o = 32; o; o >>= 1) m2 = fmaxf(m2, __shfl_xor(m2, o));
        float e = __expf(la0 - m2) + __expf(la1 - m2);
        #pragma unroll
        for (int o = 32; o; o >>= 1) e += __shfl_xor(e, o);
        if (l == 0) logZ[b] = m2 + __logf(e);
    }
}

// ================= fallback (proven R1 kernel) for small ws =================
__global__ __launch_bounds__(256) void crf_forward_fallback(
    const float* __restrict__ trans, const float* __restrict__ em,
    const int* __restrict__ seq_lens, float* __restrict__ alpha_out,
    float* __restrict__ logZ_out)
{
    const int b = blockIdx.x;
    const int tid = threadIdx.x;
    const int j = tid & (KDIM - 1);
    const int h = tid >> 7;

    __shared__ __align__(16) float p_lds[KDIM];
    __shared__ float part[KDIM];
    __shared__ float red[8];

    float Ereg[64];
    #pragma unroll
    for (int k = 0; k < 64; ++k) Ereg[k] = __expf(trans[(h * 64 + k) * KDIM + j]);

    const int len = seq_lens[b];
    const float* emb = em + (size_t)b * TLEN * KDIM;
    float* outb = alpha_out + (size_t)b * TLEN * KDIM;

    float a = 0.f, last_a = 0.f;
    if (h == 0) {
        a = emb[j];
        outb[j] = a;
        if (len == 1) last_a = a;
    }
    for (int t = 1; t < TLEN; ++t) {
        {
            float v = (h == 0) ? a : -INFINITY;
            #pragma unroll
            for (int o = 32; o >= 1; o >>= 1) v = fmaxf(v, __shfl_xor(v, o));
            if ((tid & 63) == 0) red[tid >> 6] = v;
        }
        __syncthreads();
        const float m = fmaxf(red[0], red[1]);
        if (h == 0) p_lds[j] = __expf(a - m);
        __syncthreads();
        float em_t = 0.f;
        if (h == 0) em_t = emb[t * KDIM + j];
        float acc0 = 0.f, acc1 = 0.f, acc2 = 0.f, acc3 = 0.f;
        const float4* p4 = (const float4*)(p_lds + h * 64);
        #pragma unroll
        for (int k4 = 0; k4 < 16; ++k4) {
            float4 pv = p4[k4];
            acc0 = fmaf(pv.x, Ereg[4 * k4 + 0], acc0);
            acc1 = fmaf(pv.y, Ereg[4 * k4 + 1], acc1);
            acc2 = fmaf(pv.z, Ereg[4 * k4 + 2], acc2);
            acc3 = fmaf(pv.w, Ereg[4 * k4 + 3], acc3);
        }
        const float acc = (acc0 + acc1) + (acc2 + acc3);
        if (h == 1) part[j] = acc;
        __syncthreads();
        if (h == 0) {
            const float q = acc + part[j];
            a = em_t + m + __logf(q);
            outb[t * KDIM + j] = a;
            if (t == len - 1) last_a = a;
        }
    }
    {
        float v = (h == 0) ? last_a : -INFINITY;
        #pragma unroll
        for (int o = 32; o >= 1; o >>= 1) v = fmaxf(v, __shfl_xor(v, o));
        if ((tid & 63) == 0) red[tid >> 6] = v;
    }
    __syncthreads();
    const float m2 = fmaxf(red[0], red[1]);
    float e = (h == 0) ? __expf(last_a - m2) : 0.f;
    #pragma unroll
    for (int o = 32; o >= 1; o >>= 1) e += __shfl_xor(e, o);
    if ((tid & 63) == 0) red[4 + (tid >> 6)] = e;
    __syncthreads();
    if (tid == 0) logZ_out[b] = m2 + logf(red[4] + red[5]);
}

extern "C" void kernel_launch(void* const* d_in, const int* in_sizes, int n_in,
                              void* d_out, int out_size, void* d_ws, size_t ws_size,
                              hipStream_t stream) {
    const float* trans    = (const float*)d_in[0];   // K*K
    const float* em       = (const float*)d_in[1];   // B*T*K
    const int*   seq_lens = (const int*)d_in[2];     // B

    float* alpha_out = (float*)d_out;                            // B*T*K
    float* logZ_out  = alpha_out + (size_t)BATCH * TLEN * KDIM;  // B

    char* ws = (char*)d_ws;

    // ---- preferred: fused cooperative pipeline ----
    if (ws_size >= (size_t)FUS_NEED) {
        float* aEnt = (float*)(ws + FUS_AENT);
        unsigned int* flg = (unsigned int*)(ws + FUS_FLAG);
        if (hipMemsetAsync(flg, 0, BATCH * NCH * sizeof(unsigned int), stream)
                == hipSuccess) {
            void* args[] = {(void*)&trans, (void*)&em, (void*)&seq_lens,
                            (void*)&aEnt, (void*)&flg, (void*)&alpha_out,
                            (void*)&logZ_out};
            hipError_t e = hipLaunchCooperativeKernel(
                (const void*)crf_fused, dim3(NCH, BATCH), dim3(256), args, 0, stream);
            if (e == hipSuccess) return;
            (void)hipGetLastError();   // clear the failed-launch error
        } else {
            (void)hipGetLastError();
        }
    }

    // ---- hedge: proven R2 3-kernel path ----
    if (ws_size >= (size_t)WSN_NEED) {
        _Float16* Pst  = (_Float16*)(ws + WSN_PST);
        float*    Svec = (float*)(ws + WSN_SVEC);
        float*    aEnt = (float*)(ws + WSN_AENT);
        crf_chunkcols2<<<dim3(NMAT, BATCH), 256, 0, stream>>>(trans, em, Pst, Svec);
        crf_scanw4<<<BATCH, 64, 0, stream>>>(em, Pst, Svec, aEnt);
        crf_replayw<<<dim3(NCH, BATCH), 64, 0, stream>>>(trans, em, seq_lens, aEnt,
                                                         alpha_out, logZ_out);
    } else {
        crf_forward_fallback<<<BATCH, 256, 0, stream>>>(trans, em, seq_lens,
                                                        alpha_out, logZ_out);
    }
}

// Round 5
// 152.708 us; speedup vs baseline: 4.4426x; 4.4426x over previous
//
#include <hip/hip_runtime.h>
#include <math.h>

#define KDIM 128
#define TLEN 512
#define BATCH 16
#define CH_L 16
#define NCH 32           // segments (replay blocks) per batch
#define NMAT 31          // chunk matrices: chunk c covers t in [16c+1, 16c+16]

typedef _Float16 half8 __attribute__((ext_vector_type(8)));
typedef _Float16 half4 __attribute__((ext_vector_type(4)));
typedef _Float16 half2t __attribute__((ext_vector_type(2)));
typedef float floatx4 __attribute__((ext_vector_type(4)));

#if defined(__has_builtin)
#if __has_builtin(__builtin_amdgcn_fdot2)
#define HAVE_FDOT2 1
#endif
#endif

static __device__ __forceinline__ float dot2f(half2t a, half2t b, float c) {
#ifdef HAVE_FDOT2
    return __builtin_amdgcn_fdot2(a, b, c, false);
#else
    return fmaf((float)a[0], (float)b[0], fmaf((float)a[1], (float)b[1], c));
#endif
}

// acc += dot(packed-f16 w (4 VGPRs = 8 halfs), half8 v)
static __device__ __forceinline__ float dot8(const half8 v, const float4 w, float acc) {
    const uint4 r = __builtin_bit_cast(uint4, v);
    acc = dot2f(__builtin_bit_cast(half2t, w.x), __builtin_bit_cast(half2t, r.x), acc);
    acc = dot2f(__builtin_bit_cast(half2t, w.y), __builtin_bit_cast(half2t, r.y), acc);
    acc = dot2f(__builtin_bit_cast(half2t, w.z), __builtin_bit_cast(half2t, r.z), acc);
    acc = dot2f(__builtin_bit_cast(half2t, w.w), __builtin_bit_cast(half2t, r.w), acc);
    return acc;
}

// ---------------- workspace layout (bytes) ----------------
// PST : f16 [BATCH][NMAT] chunk products; scan layout: 16B unit u = (2K+h)*64+l
//       holds P[enter=K*8+e][exit=2l+h]
// SVEC: f32 [BATCH][NMAT][128] per-enter-column log scales
#define WSN_PST   0
#define WSN_SVEC  16252928
#define WSN_AENT  16506880
#define WSN_NEED  16769024

// Frag conventions (validated):
//  A-frag tile(mt,kt): lane(quad,lm) holds A[mt*16+lm][kt*32+quad*8 .. +8]
//  B-frag tile(kt,nt): lane(quad,lm) holds B[kt*32+quad*8 .. +8][nt*16+lm]
//  C/D  tile(mt,nt):   lane(quad,lm) reg q = C[mt*16+quad*4+q][nt*16+lm]

// ============ kernel 1: chunk products (R2-proven, untouched) =================
__global__ __launch_bounds__(256, 2) void crf_chunkcols2(
    const float* __restrict__ trans, const float* __restrict__ em,
    _Float16* __restrict__ Pst, float* __restrict__ Svec)
{
    const int c = blockIdx.x;
    const int b = blockIdx.y;
    const int tid = threadIdx.x;
    const int w = tid >> 6, lane = tid & 63;
    const int quad = lane >> 4, lm = lane & 15;

    __shared__ __align__(16) _Float16 Flds[128 * 136];
    __shared__ __align__(16) _Float16 Wscr[4][4608];
    __shared__ __align__(16) float gAll[16 * KDIM];

    const int t0 = c * CH_L + 1;
    const float* emb = em + (size_t)b * TLEN * KDIM;

    {
        const int m = tid & 127, kh = tid >> 7;
        #pragma unroll
        for (int kk = 0; kk < 8; ++kk) {
            const int k0 = kh * 64 + kk * 8;
            half8 o;
            #pragma unroll
            for (int j = 0; j < 8; ++j)
                o[j] = (_Float16)__expf(trans[(k0 + j) * KDIM + m]);
            *(half8*)&Flds[m * 136 + k0] = o;
        }
    }
    {
        const int i8 = tid * 8;
        const float4 e0 = *(const float4*)&emb[t0 * KDIM + i8];
        const float4 e1 = *(const float4*)&emb[t0 * KDIM + i8 + 4];
        float4 g0, g1;
        g0.x = __expf(e0.x); g0.y = __expf(e0.y); g0.z = __expf(e0.z); g0.w = __expf(e0.w);
        g1.x = __expf(e1.x); g1.y = __expf(e1.y); g1.z = __expf(e1.z); g1.w = __expf(e1.w);
        *(float4*)&gAll[i8] = g0;
        *(float4*)&gAll[i8 + 4] = g1;
    }
    __syncthreads();

    _Float16* Wb = Wscr[w];
    float sc[2];
    half8 Bf[4][2];

    #pragma unroll
    for (int nt = 0; nt < 2; ++nt) {
        float tv[4][8];
        float cm = 0.f;
        const int n = 32 * w + nt * 16 + lm;
        #pragma unroll
        for (int kt = 0; kt < 4; ++kt) {
            const int r0 = kt * 32 + quad * 8;
            const float4 ga = *(const float4*)&gAll[r0];
            const float4 gb = *(const float4*)&gAll[r0 + 4];
            const float gg[8] = {ga.x, ga.y, ga.z, ga.w, gb.x, gb.y, gb.z, gb.w};
            const float4 ta = *(const float4*)&trans[(size_t)n * KDIM + r0];
            const float4 tb = *(const float4*)&trans[(size_t)n * KDIM + r0 + 4];
            const float tt[8] = {ta.x, ta.y, ta.z, ta.w, tb.x, tb.y, tb.z, tb.w};
            #pragma unroll
            for (int j = 0; j < 8; ++j) {
                const float v = __expf(tt[j]) * gg[j];
                tv[kt][j] = v;
                cm = fmaxf(cm, v);
            }
        }
        cm = fmaxf(cm, __shfl_xor(cm, 16));
        cm = fmaxf(cm, __shfl_xor(cm, 32));
        const float ri = 1.0f / cm;
        sc[nt] = __logf(cm);
        #pragma unroll
        for (int kt = 0; kt < 4; ++kt)
            #pragma unroll
            for (int j = 0; j < 8; ++j)
                Bf[kt][nt][j] = (_Float16)(tv[kt][j] * ri);
    }

    half8 Af[8][4];
    #pragma unroll
    for (int mt = 0; mt < 8; ++mt)
        #pragma unroll
        for (int kt = 0; kt < 4; ++kt)
            Af[mt][kt] = *(const half8*)&Flds[lm * 136 + quad * 8 + mt * 2176 + kt * 32];

    const floatx4 z4 = {0.f, 0.f, 0.f, 0.f};
    for (int it = 1; it < 16; ++it) {
        #pragma unroll
        for (int nt = 0; nt < 2; ++nt) {
            floatx4 acc[8];
            #pragma unroll
            for (int mt = 0; mt < 8; ++mt)
                acc[mt] = __builtin_amdgcn_mfma_f32_16x16x32_f16(Af[mt][0], Bf[0][nt], z4, 0, 0, 0);
            #pragma unroll
            for (int kt = 1; kt < 4; ++kt)
                #pragma unroll
                for (int mt = 0; mt < 8; ++mt)
                    acc[mt] = __builtin_amdgcn_mfma_f32_16x16x32_f16(Af[mt][kt], Bf[kt][nt], acc[mt], 0, 0, 0);

            const float* g = &gAll[it * KDIM];
            float cm = 0.f;
            #pragma unroll
            for (int mt = 0; mt < 8; ++mt) {
                const float4 gv = *(const float4*)&g[mt * 16 + quad * 4];
                floatx4 v = acc[mt];
                v.x *= gv.x; v.y *= gv.y; v.z *= gv.z; v.w *= gv.w;
                acc[mt] = v;
                cm = fmaxf(cm, fmaxf(fmaxf(v.x, v.y), fmaxf(v.z, v.w)));
            }
            cm = fmaxf(cm, __shfl_xor(cm, 16));
            cm = fmaxf(cm, __shfl_xor(cm, 32));
            const float ri = 1.0f / cm;
            sc[nt] += __logf(cm);

            if (it < 15) {
                #pragma unroll
                for (int mt = 0; mt < 8; ++mt) {
                    const floatx4 v = acc[mt];
                    half4 o;
                    o[0] = (_Float16)(v.x * ri);
                    o[1] = (_Float16)(v.y * ri);
                    o[2] = (_Float16)(v.z * ri);
                    o[3] = (_Float16)(v.w * ri);
                    *(half4*)&Wb[lm * 136 + quad * 4 + nt * 2176 + mt * 16] = o;
                }
            } else {
                #pragma unroll
                for (int mt = 0; mt < 8; ++mt) {
                    const floatx4 v = acc[mt];
                    const int ba = quad * 144 + lm + mt * 576 + nt * 16;
                    Wb[ba]       = (_Float16)(v.x * ri);
                    Wb[ba + 36]  = (_Float16)(v.y * ri);
                    Wb[ba + 72]  = (_Float16)(v.z * ri);
                    Wb[ba + 108] = (_Float16)(v.w * ri);
                }
            }
        }
        if (it < 15) {
            #pragma unroll
            for (int kt = 0; kt < 4; ++kt)
                #pragma unroll
                for (int nt = 0; nt < 2; ++nt)
                    Bf[kt][nt] = *(const half8*)&Wb[lm * 136 + quad * 8 + nt * 2176 + kt * 32];
        }
    }

    _Float16* Pc = Pst + ((size_t)(b * NMAT + c)) * 16384;
    #pragma unroll
    for (int Kl = 0; Kl < 4; ++Kl)
        #pragma unroll
        for (int hh = 0; hh < 2; ++hh) {
            const half4 lo = *(const half4*)&Wb[(2 * lane + hh) * 36 + Kl * 8];
            const half4 hi = *(const half4*)&Wb[(2 * lane + hh) * 36 + Kl * 8 + 4];
            half8 v;
            #pragma unroll
            for (int e = 0; e < 4; ++e) { v[e] = lo[e]; v[4 + e] = hi[e]; }
            const int u = (2 * (4 * w + Kl) + hh) * 64 + lane;
            *(half8*)&Pc[(size_t)u * 8] = v;
        }
    if (quad == 0) {
        float* sp = Svec + ((size_t)(b * NMAT + c)) * KDIM + 32 * w;
        sp[lm] = sc[0];
        sp[lm + 16] = sc[1];
    }
}

// ============ kernel 2: block-per-batch scan, P direct-to-register ============
// R4 post-mortem: scanw4 ran 16 waves on the whole chip, latency-bound at
// ~75-85us. Here: one 256-thread block per batch (64 waves/batch of TLP).
// Layout gift: unit u=(2K+h)*64+l means lane l of wave w needs exactly units
// rh in [8w,8w+8) at its own lane -> 8 coalesced global_load_dwordx4 per lane
// STRAIGHT INTO REGISTERS. No LDS staging, no vmcnt bookkeeping (compiler
// inserts the waitcnt at first register use). PA/PB double buffer (64 VGPR),
// static indexing via 2x-unrolled loop (rule #20); chunk c+2 issued right
// after the matvec consumes the buffer (~1.3 iters of latency slack).
// Math identical to proven scanw4: p~=exp(lq+sv-M), new = L+M+log q.
__global__ __launch_bounds__(256, 1) void crf_scanw6(
    const float* __restrict__ em, const _Float16* __restrict__ Pst,
    const float* __restrict__ Svec, float* __restrict__ aEnter)
{
    const int b = blockIdx.x;
    const int tid = threadIdx.x;
    const int w = tid >> 6, lane = tid & 63;

    __shared__ __align__(16) _Float16 pbuf[KDIM];   // p~ (f16, by enter index)
    __shared__ __align__(16) float part[4][KDIM];   // per-wave matvec partials
    __shared__ float red[2];

    const _Float16* Pb = Pst + (size_t)b * NMAT * 16384;
    const float* svb = Svec + (size_t)b * NMAT * KDIM;
    float* aeb = aEnter + (size_t)b * NCH * KDIM;

    // prologue: chunk 0 -> PA, chunk 1 -> PB (8 x dwordx4 per lane each)
    half8 PA[8], PB[8];
    #pragma unroll
    for (int i = 0; i < 8; ++i)
        PA[i] = *(const half8*)&Pb[((8 * w + i) * 64 + lane) * 8];
    #pragma unroll
    for (int i = 0; i < 8; ++i)
        PB[i] = *(const half8*)&Pb[16384 + ((8 * w + i) * 64 + lane) * 8];

    // init state: threads 0..127 own exit/enter column j = tid
    float lq = 0.f, L = 0.f, svR = 0.f, svN = 0.f;
    {
        float a0 = -INFINITY;
        if (tid < KDIM) a0 = em[(size_t)b * TLEN * KDIM + tid];
        float m = a0;
        #pragma unroll
        for (int o = 32; o; o >>= 1) m = fmaxf(m, __shfl_xor(m, o));
        if (w < 2 && lane == 0) red[w] = m;
        __syncthreads();
        const float mx = fmaxf(red[0], red[1]);
        if (tid < KDIM) {
            aeb[tid] = a0;
            lq = a0 - mx;
            L = mx;
            svR = svb[tid];
        }
        __syncthreads();
    }

    auto STEP = [&](half8 (&P)[8], int c) {
        // --- phase A: block max of (lq+sv); p~ into pbuf ---
        if (w < 2) {
            float m = lq + svR;
            #pragma unroll
            for (int o = 32; o; o >>= 1) m = fmaxf(m, __shfl_xor(m, o));
            if (lane == 0) red[w] = m;
        }
        __syncthreads();
        const float M = fmaxf(red[0], red[1]);
        if (w < 2) {
            pbuf[tid] = (_Float16)__expf(lq + svR - M);
            if (c + 1 < NMAT) svN = svb[(size_t)(c + 1) * KDIM + tid];
        }
        __syncthreads();
        // --- phase B: matvec partials; wave w covers enters 32w..32w+32 ---
        float q0 = 0.f, q1 = 0.f;
        #pragma unroll
        for (int kk = 0; kk < 4; ++kk) {
            const float4 wv = *(const float4*)&pbuf[(4 * w + kk) * 8]; // uniform->bcast
            q0 = dot8(P[2 * kk + 0], wv, q0);
            q1 = dot8(P[2 * kk + 1], wv, q1);
        }
        float2 qq; qq.x = q0; qq.y = q1;
        *(float2*)&part[w][2 * lane] = qq;
        // P consumed: issue chunk c+2 into the same register buffer
        if (c + 2 < NMAT) {
            #pragma unroll
            for (int i = 0; i < 8; ++i)
                P[i] = *(const half8*)&Pb[(size_t)(c + 2) * 16384
                                          + ((8 * w + i) * 64 + lane) * 8];
        }
        __syncthreads();
        // --- phase C: combine, log, emit, advance state ---
        if (tid < KDIM) {
            const float q = part[0][tid] + part[1][tid]
                          + part[2][tid] + part[3][tid];
            const float lg = __logf(q);
            aeb[(size_t)(c + 1) * KDIM + tid] = L + M + lg;
            lq = lg;
            L += M;
            svR = svN;
        }
    };

    for (int c = 0; c < NMAT; c += 2) {
        STEP(PA, c);
        if (c + 1 < NMAT) STEP(PB, c + 1);
    }
}

// ================= kernel 3: replayw — one wave per (chunk,batch) =============
__global__ __launch_bounds__(64, 1) void crf_replayw(
    const float* __restrict__ trans, const float* __restrict__ em,
    const int* __restrict__ seq_lens, const float* __restrict__ aEnter,
    float* __restrict__ alpha, float* __restrict__ logZ)
{
    const int c = blockIdx.x, b = blockIdx.y;
    const int l = threadIdx.x;

    __shared__ __align__(16) _Float16 pbuf[KDIM];

    half2t Ea[64], Eb[64];
    #pragma unroll
    for (int t2 = 0; t2 < 64; ++t2) {
        const float* r0 = &trans[(2 * t2) * KDIM];
        const float* r1 = &trans[(2 * t2 + 1) * KDIM];
        half2t ea, eb;
        ea[0] = (_Float16)__expf(r0[l]);
        ea[1] = (_Float16)__expf(r1[l]);
        eb[0] = (_Float16)__expf(r0[l + 64]);
        eb[1] = (_Float16)__expf(r1[l + 64]);
        Ea[t2] = ea;
        Eb[t2] = eb;
    }

    const int len = seq_lens[b];
    const float* emb = em + (size_t)b * TLEN * KDIM;
    float* outb = alpha + (size_t)b * TLEN * KDIM;
    const float* ae = aEnter + ((size_t)b * NCH + c) * KDIM;

    float a0 = ae[l], a1 = ae[l + 64];
    if (c == 0) {
        a0 = emb[l];
        a1 = emb[l + 64];
    }
    float mx = fmaxf(a0, a1);
    #pragma unroll
    for (int o = 32; o; o >>= 1) mx = fmaxf(mx, __shfl_xor(mx, o));
    float L = mx;
    pbuf[l]      = (_Float16)__expf(a0 - L);
    pbuf[l + 64] = (_Float16)__expf(a1 - L);

    float la0 = 0.f, la1 = -INFINITY;
    if (c == 0) {
        outb[l] = a0;
        outb[l + 64] = a1;
        if (len == 1) { la0 = a0; la1 = a1; }
    }

    const int t_begin = c * CH_L + 1;
    const int t_end = (c == NCH - 1) ? (TLEN - 1) : (c * CH_L + CH_L);

    float e0 = emb[t_begin * KDIM + l];
    float e1 = emb[t_begin * KDIM + l + 64];

    for (int t = t_begin; t <= t_end; ++t) {
        float n0 = 0.f, n1 = 0.f;
        if (t < t_end) {
            n0 = emb[(t + 1) * KDIM + l];
            n1 = emb[(t + 1) * KDIM + l + 64];
        }

        float q0 = 0.f, q1 = 0.f;
        #pragma unroll
        for (int s = 0; s < 16; ++s) {
            const float4 w = *(const float4*)&pbuf[s * 8];
            const half2t p0 = __builtin_bit_cast(half2t, w.x);
            const half2t p1 = __builtin_bit_cast(half2t, w.y);
            const half2t p2 = __builtin_bit_cast(half2t, w.z);
            const half2t p3 = __builtin_bit_cast(half2t, w.w);
            q0 = dot2f(p0, Ea[4 * s + 0], q0);
            q0 = dot2f(p1, Ea[4 * s + 1], q0);
            q0 = dot2f(p2, Ea[4 * s + 2], q0);
            q0 = dot2f(p3, Ea[4 * s + 3], q0);
            q1 = dot2f(p0, Eb[4 * s + 0], q1);
            q1 = dot2f(p1, Eb[4 * s + 1], q1);
            q1 = dot2f(p2, Eb[4 * s + 2], q1);
            q1 = dot2f(p3, Eb[4 * s + 3], q1);
        }

        const float A0 = e0 + L + __logf(q0);
        const float A1 = e1 + L + __logf(q1);
        outb[t * KDIM + l] = A0;
        outb[t * KDIM + l + 64] = A1;
        if (t == len - 1) { la0 = A0; la1 = A1; }

        const float sigma = __shfl(q0, 0);
        const float ri = 1.0f / sigma;
        pbuf[l]      = (_Float16)(q0 * ri * __expf(e0));
        pbuf[l + 64] = (_Float16)(q1 * ri * __expf(e1));
        L += __logf(sigma);
        e0 = n0; e1 = n1;
    }

    const bool blockowns = (len == 1) ? (c == 0) : (((len - 2) >> 4) == c);
    if (blockowns) {
        float m2 = fmaxf(la0, la1);
        #pragma unroll
        for (int o = 32; o; o >>= 1) m2 = fmaxf(m2, __shfl_xor(m2, o));
        float e = __expf(la0 - m2) + __expf(la1 - m2);
        #pragma unroll
        for (int o = 32; o; o >>= 1) e += __shfl_xor(e, o);
        if (l == 0) logZ[b] = m2 + __logf(e);
    }
}

// ================= fallback (proven R1 kernel) for small ws =================
__global__ __launch_bounds__(256) void crf_forward_fallback(
    const float* __restrict__ trans, const float* __restrict__ em,
    const int* __restrict__ seq_lens, float* __restrict__ alpha_out,
    float* __restrict__ logZ_out)
{
    const int b = blockIdx.x;
    const int tid = threadIdx.x;
    const int j = tid & (KDIM - 1);
    const int h = tid >> 7;

    __shared__ __align__(16) float p_lds[KDIM];
    __shared__ float part[KDIM];
    __shared__ float red[8];

    float Ereg[64];
    #pragma unroll
    for (int k = 0; k < 64; ++k) Ereg[k] = __expf(trans[(h * 64 + k) * KDIM + j]);

    const int len = seq_lens[b];
    const float* emb = em + (size_t)b * TLEN * KDIM;
    float* outb = alpha_out + (size_t)b * TLEN * KDIM;

    float a = 0.f, last_a = 0.f;
    if (h == 0) {
        a = emb[j];
        outb[j] = a;
        if (len == 1) last_a = a;
    }
    for (int t = 1; t < TLEN; ++t) {
        {
            float v = (h == 0) ? a : -INFINITY;
            #pragma unroll
            for (int o = 32; o >= 1; o >>= 1) v = fmaxf(v, __shfl_xor(v, o));
            if ((tid & 63) == 0) red[tid >> 6] = v;
        }
        __syncthreads();
        const float m = fmaxf(red[0], red[1]);
        if (h == 0) p_lds[j] = __expf(a - m);
        __syncthreads();
        float em_t = 0.f;
        if (h == 0) em_t = emb[t * KDIM + j];
        float acc0 = 0.f, acc1 = 0.f, acc2 = 0.f, acc3 = 0.f;
        const float4* p4 = (const float4*)(p_lds + h * 64);
        #pragma unroll
        for (int k4 = 0; k4 < 16; ++k4) {
            float4 pv = p4[k4];
            acc0 = fmaf(pv.x, Ereg[4 * k4 + 0], acc0);
            acc1 = fmaf(pv.y, Ereg[4 * k4 + 1], acc1);
            acc2 = fmaf(pv.z, Ereg[4 * k4 + 2], acc2);
            acc3 = fmaf(pv.w, Ereg[4 * k4 + 3], acc3);
        }
        const float acc = (acc0 + acc1) + (acc2 + acc3);
        if (h == 1) part[j] = acc;
        __syncthreads();
        if (h == 0) {
            const float q = acc + part[j];
            a = em_t + m + __logf(q);
            outb[t * KDIM + j] = a;
            if (t == len - 1) last_a = a;
        }
    }
    {
        float v = (h == 0) ? last_a : -INFINITY;
        #pragma unroll
        for (int o = 32; o >= 1; o >>= 1) v = fmaxf(v, __shfl_xor(v, o));
        if ((tid & 63) == 0) red[tid >> 6] = v;
    }
    __syncthreads();
    const float m2 = fmaxf(red[0], red[1]);
    float e = (h == 0) ? __expf(last_a - m2) : 0.f;
    #pragma unroll
    for (int o = 32; o >= 1; o >>= 1) e += __shfl_xor(e, o);
    if ((tid & 63) == 0) red[4 + (tid >> 6)] = e;
    __syncthreads();
    if (tid == 0) logZ_out[b] = m2 + logf(red[4] + red[5]);
}

extern "C" void kernel_launch(void* const* d_in, const int* in_sizes, int n_in,
                              void* d_out, int out_size, void* d_ws, size_t ws_size,
                              hipStream_t stream) {
    const float* trans    = (const float*)d_in[0];   // K*K
    const float* em       = (const float*)d_in[1];   // B*T*K
    const int*   seq_lens = (const int*)d_in[2];     // B

    float* alpha_out = (float*)d_out;                            // B*T*K
    float* logZ_out  = alpha_out + (size_t)BATCH * TLEN * KDIM;  // B

    char* ws = (char*)d_ws;

    if (ws_size >= (size_t)WSN_NEED) {
        _Float16* Pst  = (_Float16*)(ws + WSN_PST);
        float*    Svec = (float*)(ws + WSN_SVEC);
        float*    aEnt = (float*)(ws + WSN_AENT);
        crf_chunkcols2<<<dim3(NMAT, BATCH), 256, 0, stream>>>(trans, em, Pst, Svec);
        crf_scanw6<<<BATCH, 256, 0, stream>>>(em, Pst, Svec, aEnt);
        crf_replayw<<<dim3(NCH, BATCH), 64, 0, stream>>>(trans, em, seq_lens, aEnt,
                                                         alpha_out, logZ_out);
    } else {
        crf_forward_fallback<<<BATCH, 256, 0, stream>>>(trans, em, seq_lens,
                                                        alpha_out, logZ_out);
    }
}

// Round 6
// 151.243 us; speedup vs baseline: 4.4856x; 1.0097x over previous
//
#include <hip/hip_runtime.h>
#include <math.h>

#define KDIM 128
#define TLEN 512
#define BATCH 16
#define CH_L 16
#define NCH 32           // segments (replay blocks) per batch
#define NMAT 31          // chunk matrices: chunk c covers t in [16c+1, 16c+16]

typedef _Float16 half8 __attribute__((ext_vector_type(8)));
typedef _Float16 half4 __attribute__((ext_vector_type(4)));
typedef _Float16 half2t __attribute__((ext_vector_type(2)));
typedef float floatx4 __attribute__((ext_vector_type(4)));

#if defined(__has_builtin)
#if __has_builtin(__builtin_amdgcn_fdot2)
#define HAVE_FDOT2 1
#endif
#endif

static __device__ __forceinline__ float dot2f(half2t a, half2t b, float c) {
#ifdef HAVE_FDOT2
    return __builtin_amdgcn_fdot2(a, b, c, false);
#else
    return fmaf((float)a[0], (float)b[0], fmaf((float)a[1], (float)b[1], c));
#endif
}

// acc += dot(packed-f16 w (4 VGPRs = 8 halfs), half8 v)
static __device__ __forceinline__ float dot8(const half8 v, const float4 w, float acc) {
    const uint4 r = __builtin_bit_cast(uint4, v);
    acc = dot2f(__builtin_bit_cast(half2t, w.x), __builtin_bit_cast(half2t, r.x), acc);
    acc = dot2f(__builtin_bit_cast(half2t, w.y), __builtin_bit_cast(half2t, r.y), acc);
    acc = dot2f(__builtin_bit_cast(half2t, w.z), __builtin_bit_cast(half2t, r.z), acc);
    acc = dot2f(__builtin_bit_cast(half2t, w.w), __builtin_bit_cast(half2t, r.w), acc);
    return acc;
}

// ---- asm-anchored loads: volatile asm pins ISSUE ORDER at source position and
// its outputs cannot be rematerialized-from-memory by the register allocator
// (the R2/R3/R5 hoist/sink failures cannot happen to these). Waiting is done
// explicitly with counted s_waitcnt vmcnt(N).
static __device__ __forceinline__ half8 gload16_asm(const _Float16* p) {
    half8 r;
    asm volatile("global_load_dwordx4 %0, %1, off" : "=v"(r) : "v"(p));
    return r;
}
static __device__ __forceinline__ float gload4_asm(const float* p) {
    float r;
    asm volatile("global_load_dword %0, %1, off" : "=v"(r) : "v"(p));
    return r;
}

// ---------------- workspace layout (bytes) ----------------
// PST : f16 [BATCH][NMAT] chunk products; scan layout: 16B unit u = (2K+h)*64+l
//       holds P[enter=K*8+e][exit=2l+h]
// SVEC: f32 [BATCH][NMAT][128] per-enter-column log scales
#define WSN_PST   0
#define WSN_SVEC  16252928
#define WSN_AENT  16506880
#define WSN_NEED  16769024

// Frag conventions (validated):
//  A-frag tile(mt,kt): lane(quad,lm) holds A[mt*16+lm][kt*32+quad*8 .. +8]
//  B-frag tile(kt,nt): lane(quad,lm) holds B[kt*32+quad*8 .. +8][nt*16+lm]
//  C/D  tile(mt,nt):   lane(quad,lm) reg q = C[mt*16+quad*4+q][nt*16+lm]

// ============ kernel 1: chunk products (R2-proven loop; 1D XCD-local grid) ====
// Grid = 496 blocks, 1D. Mapping keeps batch b on XCD b%8 (round-robin
// dispatch assumption): r=bid&7, j=bid>>3; b = r (+8 if j>=31); c = j mod 31.
// Scan block b also round-robins to XCD b%8 -> batch b's 1MB Pst slice is
// likely L2-resident for the scan (4MB/XCD). Perf-heuristic only.
__global__ __launch_bounds__(256, 2) void crf_chunkcols2(
    const float* __restrict__ trans, const float* __restrict__ em,
    _Float16* __restrict__ Pst, float* __restrict__ Svec)
{
    const int bid = blockIdx.x;
    const int r = bid & 7, j = bid >> 3;
    const int b = (j < NMAT) ? r : r + 8;
    const int c = (j < NMAT) ? j : j - NMAT;
    const int tid = threadIdx.x;
    const int w = tid >> 6, lane = tid & 63;
    const int quad = lane >> 4, lm = lane & 15;

    __shared__ __align__(16) _Float16 Flds[128 * 136];
    __shared__ __align__(16) _Float16 Wscr[4][4608];
    __shared__ __align__(16) float gAll[16 * KDIM];

    const int t0 = c * CH_L + 1;
    const float* emb = em + (size_t)b * TLEN * KDIM;

    {
        const int m = tid & 127, kh = tid >> 7;
        #pragma unroll
        for (int kk = 0; kk < 8; ++kk) {
            const int k0 = kh * 64 + kk * 8;
            half8 o;
            #pragma unroll
            for (int jj = 0; jj < 8; ++jj)
                o[jj] = (_Float16)__expf(trans[(k0 + jj) * KDIM + m]);
            *(half8*)&Flds[m * 136 + k0] = o;
        }
    }
    {
        const int i8 = tid * 8;
        const float4 e0 = *(const float4*)&emb[t0 * KDIM + i8];
        const float4 e1 = *(const float4*)&emb[t0 * KDIM + i8 + 4];
        float4 g0, g1;
        g0.x = __expf(e0.x); g0.y = __expf(e0.y); g0.z = __expf(e0.z); g0.w = __expf(e0.w);
        g1.x = __expf(e1.x); g1.y = __expf(e1.y); g1.z = __expf(e1.z); g1.w = __expf(e1.w);
        *(float4*)&gAll[i8] = g0;
        *(float4*)&gAll[i8 + 4] = g1;
    }
    __syncthreads();

    _Float16* Wb = Wscr[w];
    float sc[2];
    half8 Bf[4][2];

    #pragma unroll
    for (int nt = 0; nt < 2; ++nt) {
        float tv[4][8];
        float cm = 0.f;
        const int n = 32 * w + nt * 16 + lm;
        #pragma unroll
        for (int kt = 0; kt < 4; ++kt) {
            const int r0 = kt * 32 + quad * 8;
            const float4 ga = *(const float4*)&gAll[r0];
            const float4 gb = *(const float4*)&gAll[r0 + 4];
            const float gg[8] = {ga.x, ga.y, ga.z, ga.w, gb.x, gb.y, gb.z, gb.w};
            const float4 ta = *(const float4*)&trans[(size_t)n * KDIM + r0];
            const float4 tb = *(const float4*)&trans[(size_t)n * KDIM + r0 + 4];
            const float tt[8] = {ta.x, ta.y, ta.z, ta.w, tb.x, tb.y, tb.z, tb.w};
            #pragma unroll
            for (int jj = 0; jj < 8; ++jj) {
                const float v = __expf(tt[jj]) * gg[jj];
                tv[kt][jj] = v;
                cm = fmaxf(cm, v);
            }
        }
        cm = fmaxf(cm, __shfl_xor(cm, 16));
        cm = fmaxf(cm, __shfl_xor(cm, 32));
        const float ri = 1.0f / cm;
        sc[nt] = __logf(cm);
        #pragma unroll
        for (int kt = 0; kt < 4; ++kt)
            #pragma unroll
            for (int jj = 0; jj < 8; ++jj)
                Bf[kt][nt][jj] = (_Float16)(tv[kt][jj] * ri);
    }

    half8 Af[8][4];
    #pragma unroll
    for (int mt = 0; mt < 8; ++mt)
        #pragma unroll
        for (int kt = 0; kt < 4; ++kt)
            Af[mt][kt] = *(const half8*)&Flds[lm * 136 + quad * 8 + mt * 2176 + kt * 32];

    const floatx4 z4 = {0.f, 0.f, 0.f, 0.f};
    for (int it = 1; it < 16; ++it) {
        #pragma unroll
        for (int nt = 0; nt < 2; ++nt) {
            floatx4 acc[8];
            #pragma unroll
            for (int mt = 0; mt < 8; ++mt)
                acc[mt] = __builtin_amdgcn_mfma_f32_16x16x32_f16(Af[mt][0], Bf[0][nt], z4, 0, 0, 0);
            #pragma unroll
            for (int kt = 1; kt < 4; ++kt)
                #pragma unroll
                for (int mt = 0; mt < 8; ++mt)
                    acc[mt] = __builtin_amdgcn_mfma_f32_16x16x32_f16(Af[mt][kt], Bf[kt][nt], acc[mt], 0, 0, 0);

            const float* g = &gAll[it * KDIM];
            float cm = 0.f;
            #pragma unroll
            for (int mt = 0; mt < 8; ++mt) {
                const float4 gv = *(const float4*)&g[mt * 16 + quad * 4];
                floatx4 v = acc[mt];
                v.x *= gv.x; v.y *= gv.y; v.z *= gv.z; v.w *= gv.w;
                acc[mt] = v;
                cm = fmaxf(cm, fmaxf(fmaxf(v.x, v.y), fmaxf(v.z, v.w)));
            }
            cm = fmaxf(cm, __shfl_xor(cm, 16));
            cm = fmaxf(cm, __shfl_xor(cm, 32));
            const float ri = 1.0f / cm;
            sc[nt] += __logf(cm);

            if (it < 15) {
                #pragma unroll
                for (int mt = 0; mt < 8; ++mt) {
                    const floatx4 v = acc[mt];
                    half4 o;
                    o[0] = (_Float16)(v.x * ri);
                    o[1] = (_Float16)(v.y * ri);
                    o[2] = (_Float16)(v.z * ri);
                    o[3] = (_Float16)(v.w * ri);
                    *(half4*)&Wb[lm * 136 + quad * 4 + nt * 2176 + mt * 16] = o;
                }
            } else {
                #pragma unroll
                for (int mt = 0; mt < 8; ++mt) {
                    const floatx4 v = acc[mt];
                    const int ba = quad * 144 + lm + mt * 576 + nt * 16;
                    Wb[ba]       = (_Float16)(v.x * ri);
                    Wb[ba + 36]  = (_Float16)(v.y * ri);
                    Wb[ba + 72]  = (_Float16)(v.z * ri);
                    Wb[ba + 108] = (_Float16)(v.w * ri);
                }
            }
        }
        if (it < 15) {
            #pragma unroll
            for (int kt = 0; kt < 4; ++kt)
                #pragma unroll
                for (int nt = 0; nt < 2; ++nt)
                    Bf[kt][nt] = *(const half8*)&Wb[lm * 136 + quad * 8 + nt * 2176 + kt * 32];
        }
    }

    _Float16* Pc = Pst + ((size_t)(b * NMAT + c)) * 16384;
    #pragma unroll
    for (int Kl = 0; Kl < 4; ++Kl)
        #pragma unroll
        for (int hh = 0; hh < 2; ++hh) {
            const half4 lo = *(const half4*)&Wb[(2 * lane + hh) * 36 + Kl * 8];
            const half4 hi = *(const half4*)&Wb[(2 * lane + hh) * 36 + Kl * 8 + 4];
            half8 v;
            #pragma unroll
            for (int e = 0; e < 4; ++e) { v[e] = lo[e]; v[4 + e] = hi[e]; }
            const int u = (2 * (4 * w + Kl) + hh) * 64 + lane;
            *(half8*)&Pc[(size_t)u * 8] = v;
        }
    if (quad == 0) {
        float* sp = Svec + ((size_t)(b * NMAT + c)) * KDIM + 32 * w;
        sp[lm] = sc[0];
        sp[lm + 16] = sc[1];
    }
}

// ============ kernel 2: scan with asm-anchored pipelined prefetch =============
// R5 post-mortem: two different scans landed within 4us because the compiler
// SANK the register prefetch to its use -> every iteration paid a serial
// memory round trip. Here every loop vmem op is issued by volatile inline asm
// (un-sinkable, un-rematerializable) in groups of 9 (8x dwordx4 P + 1x dword
// sv) per chunk, issued at the END of step c for chunk c+2. The wait at the
// top of step c is exactly vmcnt(9): the newest 9 outstanding ops are chunk
// c+1's group, everything older (chunk c's group + phase-C store) drains.
// Tail step uses vmcnt(0). sched_barrier(0) after each wait (rule #18).
__global__ __launch_bounds__(256, 1) void crf_scanw8(
    const float* __restrict__ em, const _Float16* __restrict__ Pst,
    const float* __restrict__ Svec, float* __restrict__ aEnter)
{
    const int b = blockIdx.x;
    const int tid = threadIdx.x;
    const int w = tid >> 6, lane = tid & 63;

    __shared__ __align__(16) _Float16 pbuf[KDIM];   // p~ (f16, by enter index)
    __shared__ __align__(16) float part[4][KDIM];   // per-wave matvec partials
    __shared__ float red[2];

    const _Float16* Pb = Pst + (size_t)b * NMAT * 16384;
    const float* svb = Svec + (size_t)b * NMAT * KDIM;
    float* aeb = aEnter + (size_t)b * NCH * KDIM;
    const int jsv = tid & 127;                       // sv column this thread tracks

    // prologue: groups G(0) and G(1), 9 asm ops each
    half8 PA[8], PB[8];
    float svA, svB;
    #pragma unroll
    for (int i = 0; i < 8; ++i)
        PA[i] = gload16_asm(&Pb[((8 * w + i) * 64 + lane) * 8]);
    svA = gload4_asm(&svb[jsv]);
    #pragma unroll
    for (int i = 0; i < 8; ++i)
        PB[i] = gload16_asm(&Pb[16384 + ((8 * w + i) * 64 + lane) * 8]);
    svB = gload4_asm(&svb[KDIM + jsv]);

    // init state: threads 0..127 own exit/enter column j = tid
    float lq = 0.f, L = 0.f;
    {
        float a0 = -INFINITY;
        if (tid < KDIM) a0 = em[(size_t)b * TLEN * KDIM + tid];
        float m = a0;
        #pragma unroll
        for (int o = 32; o; o >>= 1) m = fmaxf(m, __shfl_xor(m, o));
        if (w < 2 && lane == 0) red[w] = m;
        __syncthreads();
        const float mx = fmaxf(red[0], red[1]);
        if (tid < KDIM) {
            aeb[tid] = a0;
            lq = a0 - mx;
            L = mx;
        }
        __syncthreads();
    }

    auto STEP = [&](half8 (&P)[8], float& sv, int c) {
        // --- wait: chunk c's group (and older) retired; c+1's stays in flight
        if (c == NMAT - 1) {
            asm volatile("s_waitcnt vmcnt(0)" ::: "memory");
        } else {
            asm volatile("s_waitcnt vmcnt(9)" ::: "memory");
        }
        __builtin_amdgcn_sched_barrier(0);

        // --- phase A: block max of (lq+sv); p~ into pbuf ---
        if (w < 2) {
            float m = lq + sv;
            #pragma unroll
            for (int o = 32; o; o >>= 1) m = fmaxf(m, __shfl_xor(m, o));
            if (lane == 0) red[w] = m;
        }
        __syncthreads();
        const float M = fmaxf(red[0], red[1]);
        if (w < 2)
            pbuf[tid] = (_Float16)__expf(lq + sv - M);
        __syncthreads();

        // --- phase B: matvec partials; wave w covers enters 32w..32w+32 ---
        float q0 = 0.f, q1 = 0.f;
        #pragma unroll
        for (int kk = 0; kk < 4; ++kk) {
            const float4 wv = *(const float4*)&pbuf[(4 * w + kk) * 8]; // bcast
            q0 = dot8(P[2 * kk + 0], wv, q0);
            q1 = dot8(P[2 * kk + 1], wv, q1);
        }
        float2 qq; qq.x = q0; qq.y = q1;
        *(float2*)&part[w][2 * lane] = qq;
        __syncthreads();

        // --- phase C: combine, log, emit, advance state ---
        if (tid < KDIM) {
            const float q = part[0][tid] + part[1][tid]
                          + part[2][tid] + part[3][tid];
            const float lg = __logf(q);
            aeb[(size_t)(c + 1) * KDIM + tid] = L + M + lg;
            lq = lg;
            L += M;
        }

        // --- issue group G(c+2) into the just-consumed buffer ---
        if (c + 2 < NMAT) {
            #pragma unroll
            for (int i = 0; i < 8; ++i)
                P[i] = gload16_asm(&Pb[(size_t)(c + 2) * 16384
                                       + ((8 * w + i) * 64 + lane) * 8]);
            sv = gload4_asm(&svb[(size_t)(c + 2) * KDIM + jsv]);
        }
    };

    for (int c = 0; c < NMAT; c += 2) {
        STEP(PA, svA, c);
        if (c + 1 < NMAT) STEP(PB, svB, c + 1);
    }
}

// ================= kernel 3: replayw — one wave per (chunk,batch) =============
__global__ __launch_bounds__(64, 1) void crf_replayw(
    const float* __restrict__ trans, const float* __restrict__ em,
    const int* __restrict__ seq_lens, const float* __restrict__ aEnter,
    float* __restrict__ alpha, float* __restrict__ logZ)
{
    const int c = blockIdx.x, b = blockIdx.y;
    const int l = threadIdx.x;

    __shared__ __align__(16) _Float16 pbuf[KDIM];

    half2t Ea[64], Eb[64];
    #pragma unroll
    for (int t2 = 0; t2 < 64; ++t2) {
        const float* r0 = &trans[(2 * t2) * KDIM];
        const float* r1 = &trans[(2 * t2 + 1) * KDIM];
        half2t ea, eb;
        ea[0] = (_Float16)__expf(r0[l]);
        ea[1] = (_Float16)__expf(r1[l]);
        eb[0] = (_Float16)__expf(r0[l + 64]);
        eb[1] = (_Float16)__expf(r1[l + 64]);
        Ea[t2] = ea;
        Eb[t2] = eb;
    }

    const int len = seq_lens[b];
    const float* emb = em + (size_t)b * TLEN * KDIM;
    float* outb = alpha + (size_t)b * TLEN * KDIM;
    const float* ae = aEnter + ((size_t)b * NCH + c) * KDIM;

    float a0 = ae[l], a1 = ae[l + 64];
    if (c == 0) {
        a0 = emb[l];
        a1 = emb[l + 64];
    }
    float mx = fmaxf(a0, a1);
    #pragma unroll
    for (int o = 32; o; o >>= 1) mx = fmaxf(mx, __shfl_xor(mx, o));
    float L = mx;
    pbuf[l]      = (_Float16)__expf(a0 - L);
    pbuf[l + 64] = (_Float16)__expf(a1 - L);

    float la0 = 0.f, la1 = -INFINITY;
    if (c == 0) {
        outb[l] = a0;
        outb[l + 64] = a1;
        if (len == 1) { la0 = a0; la1 = a1; }
    }

    const int t_begin = c * CH_L + 1;
    const int t_end = (c == NCH - 1) ? (TLEN - 1) : (c * CH_L + CH_L);

    float e0 = emb[t_begin * KDIM + l];
    float e1 = emb[t_begin * KDIM + l + 64];

    for (int t = t_begin; t <= t_end; ++t) {
        float n0 = 0.f, n1 = 0.f;
        if (t < t_end) {
            n0 = emb[(t + 1) * KDIM + l];
            n1 = emb[(t + 1) * KDIM + l + 64];
        }

        float q0 = 0.f, q1 = 0.f;
        #pragma unroll
        for (int s = 0; s < 16; ++s) {
            const float4 w = *(const float4*)&pbuf[s * 8];
            const half2t p0 = __builtin_bit_cast(half2t, w.x);
            const half2t p1 = __builtin_bit_cast(half2t, w.y);
            const half2t p2 = __builtin_bit_cast(half2t, w.z);
            const half2t p3 = __builtin_bit_cast(half2t, w.w);
            q0 = dot2f(p0, Ea[4 * s + 0], q0);
            q0 = dot2f(p1, Ea[4 * s + 1], q0);
            q0 = dot2f(p2, Ea[4 * s + 2], q0);
            q0 = dot2f(p3, Ea[4 * s + 3], q0);
            q1 = dot2f(p0, Eb[4 * s + 0], q1);
            q1 = dot2f(p1, Eb[4 * s + 1], q1);
            q1 = dot2f(p2, Eb[4 * s + 2], q1);
            q1 = dot2f(p3, Eb[4 * s + 3], q1);
        }

        const float A0 = e0 + L + __logf(q0);
        const float A1 = e1 + L + __logf(q1);
        outb[t * KDIM + l] = A0;
        outb[t * KDIM + l + 64] = A1;
        if (t == len - 1) { la0 = A0; la1 = A1; }

        const float sigma = __shfl(q0, 0);
        const float ri = 1.0f / sigma;
        pbuf[l]      = (_Float16)(q0 * ri * __expf(e0));
        pbuf[l + 64] = (_Float16)(q1 * ri * __expf(e1));
        L += __logf(sigma);
        e0 = n0; e1 = n1;
    }

    const bool blockowns = (len == 1) ? (c == 0) : (((len - 2) >> 4) == c);
    if (blockowns) {
        float m2 = fmaxf(la0, la1);
        #pragma unroll
        for (int o = 32; o; o >>= 1) m2 = fmaxf(m2, __shfl_xor(m2, o));
        float e = __expf(la0 - m2) + __expf(la1 - m2);
        #pragma unroll
        for (int o = 32; o; o >>= 1) e += __shfl_xor(e, o);
        if (l == 0) logZ[b] = m2 + __logf(e);
    }
}

// ================= fallback (proven R1 kernel) for small ws =================
__global__ __launch_bounds__(256) void crf_forward_fallback(
    const float* __restrict__ trans, const float* __restrict__ em,
    const int* __restrict__ seq_lens, float* __restrict__ alpha_out,
    float* __restrict__ logZ_out)
{
    const int b = blockIdx.x;
    const int tid = threadIdx.x;
    const int j = tid & (KDIM - 1);
    const int h = tid >> 7;

    __shared__ __align__(16) float p_lds[KDIM];
    __shared__ float part[KDIM];
    __shared__ float red[8];

    float Ereg[64];
    #pragma unroll
    for (int k = 0; k < 64; ++k) Ereg[k] = __expf(trans[(h * 64 + k) * KDIM + j]);

    const int len = seq_lens[b];
    const float* emb = em + (size_t)b * TLEN * KDIM;
    float* outb = alpha_out + (size_t)b * TLEN * KDIM;

    float a = 0.f, last_a = 0.f;
    if (h == 0) {
        a = emb[j];
        outb[j] = a;
        if (len == 1) last_a = a;
    }
    for (int t = 1; t < TLEN; ++t) {
        {
            float v = (h == 0) ? a : -INFINITY;
            #pragma unroll
            for (int o = 32; o >= 1; o >>= 1) v = fmaxf(v, __shfl_xor(v, o));
            if ((tid & 63) == 0) red[tid >> 6] = v;
        }
        __syncthreads();
        const float m = fmaxf(red[0], red[1]);
        if (h == 0) p_lds[j] = __expf(a - m);
        __syncthreads();
        float em_t = 0.f;
        if (h == 0) em_t = emb[t * KDIM + j];
        float acc0 = 0.f, acc1 = 0.f, acc2 = 0.f, acc3 = 0.f;
        const float4* p4 = (const float4*)(p_lds + h * 64);
        #pragma unroll
        for (int k4 = 0; k4 < 16; ++k4) {
            float4 pv = p4[k4];
            acc0 = fmaf(pv.x, Ereg[4 * k4 + 0], acc0);
            acc1 = fmaf(pv.y, Ereg[4 * k4 + 1], acc1);
            acc2 = fmaf(pv.z, Ereg[4 * k4 + 2], acc2);
            acc3 = fmaf(pv.w, Ereg[4 * k4 + 3], acc3);
        }
        const float acc = (acc0 + acc1) + (acc2 + acc3);
        if (h == 1) part[j] = acc;
        __syncthreads();
        if (h == 0) {
            const float q = acc + part[j];
            a = em_t + m + __logf(q);
            outb[t * KDIM + j] = a;
            if (t == len - 1) last_a = a;
        }
    }
    {
        float v = (h == 0) ? last_a : -INFINITY;
        #pragma unroll
        for (int o = 32; o >= 1; o >>= 1) v = fmaxf(v, __shfl_xor(v, o));
        if ((tid & 63) == 0) red[tid >> 6] = v;
    }
    __syncthreads();
    const float m2 = fmaxf(red[0], red[1]);
    float e = (h == 0) ? __expf(last_a - m2) : 0.f;
    #pragma unroll
    for (int o = 32; o >= 1; o >>= 1) e += __shfl_xor(e, o);
    if ((tid & 63) == 0) red[4 + (tid >> 6)] = e;
    __syncthreads();
    if (tid == 0) logZ_out[b] = m2 + logf(red[4] + red[5]);
}

extern "C" void kernel_launch(void* const* d_in, const int* in_sizes, int n_in,
                              void* d_out, int out_size, void* d_ws, size_t ws_size,
                              hipStream_t stream) {
    const float* trans    = (const float*)d_in[0];   // K*K
    const float* em       = (const float*)d_in[1];   // B*T*K
    const int*   seq_lens = (const int*)d_in[2];     // B

    float* alpha_out = (float*)d_out;                            // B*T*K
    float* logZ_out  = alpha_out + (size_t)BATCH * TLEN * KDIM;  // B

    char* ws = (char*)d_ws;

    if (ws_size >= (size_t)WSN_NEED) {
        _Float16* Pst  = (_Float16*)(ws + WSN_PST);
        float*    Svec = (float*)(ws + WSN_SVEC);
        float*    aEnt = (float*)(ws + WSN_AENT);
        crf_chunkcols2<<<NMAT * BATCH, 256, 0, stream>>>(trans, em, Pst, Svec);
        crf_scanw8<<<BATCH, 256, 0, stream>>>(em, Pst, Svec, aEnt);
        crf_replayw<<<dim3(NCH, BATCH), 64, 0, stream>>>(trans, em, seq_lens, aEnt,
                                                         alpha_out, logZ_out);
    } else {
        crf_forward_fallback<<<BATCH, 256, 0, stream>>>(trans, em, seq_lens,
                                                        alpha_out, logZ_out);
    }
}